// Round 11
// baseline (62.613 us; speedup 1.0000x reference)
//
#include <hip/hip_runtime.h>

#define D_DIM 1024
#define H_DIM 64
#define T_SEQ 2048
#define B_SZ  8
#define M_TOT (B_SZ * T_SEQ)

typedef __attribute__((ext_vector_type(4))) float f32x4;
typedef __attribute__((ext_vector_type(8))) short s16x8;
typedef __attribute__((ext_vector_type(8))) unsigned short u16x8;
typedef __attribute__((ext_vector_type(4))) unsigned short u16x4;

__device__ __forceinline__ unsigned short f2bf(float x) {
    union { float f; unsigned u; } v; v.f = x;
    unsigned r = (v.u + 0x7FFFu + ((v.u >> 16) & 1u)) >> 16;   // RNE
    return (unsigned short)r;
}
__device__ __forceinline__ float bf2f(unsigned short u) {
    union { unsigned u; float f; } v; v.u = ((unsigned)u) << 16; return v.f;
}

__device__ __forceinline__ f32x4 mfma_bf16(u16x8 a, u16x8 b, f32x4 c) {
    return __builtin_amdgcn_mfma_f32_16x16x32_bf16(
        __builtin_bit_cast(s16x8, a), __builtin_bit_cast(s16x8, b), c, 0, 0, 0);
}

// async global->LDS, 16B/lane: LDS dest = wave-uniform base + lane*16
__device__ __forceinline__ void gload_lds16(const unsigned short* g, unsigned short* l) {
    __builtin_amdgcn_global_load_lds(
        (const __attribute__((address_space(1))) void*)g,
        (__attribute__((address_space(3))) void*)l, 16, 0, 0);
}

// ---------------------------------------------------------------------------
// Kernel 0: prep = x fp32->bf16 stream convert (blocks 0..1023, m13-style)
//         + WF build (blocks 1024..1071, fused old wtrans).
// WF[fid][lane][slot8]: fid = ks*24 + (mat*4+colTile)*2 + kh; 1KB/fragment.
// ---------------------------------------------------------------------------
__global__ __launch_bounds__(256) void prep_kernel(
    const float* __restrict__ x, const float* __restrict__ Wq,
    const float* __restrict__ Wk, const float* __restrict__ Wv,
    unsigned short* __restrict__ xb, unsigned short* __restrict__ WF)
{
    __shared__ unsigned short tw[64 * 72];
    const int tid = threadIdx.x;
    const int bid = blockIdx.x;

    if (bid < 1024) {
        // ---- pure stream convert: 64KB fp32 in, 32KB bf16 out per block ----
        const float4* x4 = reinterpret_cast<const float4*>(x);
        const size_t base = (size_t)bid * 4096 + tid;    // float4 units
        float4 v[16];
        #pragma unroll
        for (int j = 0; j < 16; ++j) v[j] = x4[base + (size_t)j * 256];
        #pragma unroll
        for (int j = 0; j < 16; ++j) {
            u16x4 u = { f2bf(v[j].x), f2bf(v[j].y), f2bf(v[j].z), f2bf(v[j].w) };
            *reinterpret_cast<u16x4*>(&xb[(base + (size_t)j * 256) * 4]) = u;
        }
        return;
    }

    // ---- WF build ----
    const int wbid = bid - 1024;
    const int mat = wbid / 16;
    const int k0  = (wbid % 16) * 64;
    const int ks  = k0 >> 6;
    const float* W = (mat == 0) ? Wq : (mat == 1) ? Wk : Wv;
    {
        const int r = tid >> 2, c0 = (tid & 3) * 16;
        #pragma unroll
        for (int jj = 0; jj < 4; ++jj) {
            float4 v = *reinterpret_cast<const float4*>(&W[(size_t)(k0 + r) * H_DIM + c0 + jj * 4]);
            u16x4 u = { f2bf(v.x), f2bf(v.y), f2bf(v.z), f2bf(v.w) };
            *reinterpret_cast<u16x4*>(&tw[r * 72 + c0 + jj * 4]) = u;
        }
    }
    __syncthreads();
    #pragma unroll
    for (int sb = 0; sb < 2; ++sb) {
        const int s    = sb * 256 + tid;
        const int ct_l = s >> 7;
        const int kh   = (s >> 6) & 1;
        const int lane = s & 63;
        const int gg = lane >> 4, nn = lane & 15;
        const int cl = ct_l * 16 + nn;
        const int kl = kh * 32 + gg * 8;
        unsigned short tmp[8];
        #pragma unroll
        for (int t = 0; t < 8; ++t) tmp[t] = tw[(kl + t) * 72 + cl];
        const int fid = ks * 24 + (mat * 4 + ct_l) * 2 + kh;
        *reinterpret_cast<u16x8*>(&WF[((size_t)fid * 64 + lane) * 8]) =
            *reinterpret_cast<const u16x8*>(tmp);
    }
}

// ---------------------------------------------------------------------------
// Kernel 1: QKV projection v8.  M=64, grid 256, 512 threads = 8 waves.
// x already bf16 (L3-resident): 1 u16x8 load + 1 ds_write per thread/iter,
// 1-deep reg prefetch.  W via global_load_lds (24 x 1KB frags/iter).
// 2 barriers/iter, 12 MFMA/iter.
// ---------------------------------------------------------------------------
__global__ __launch_bounds__(512) void qkv_proj_kernel(
    const unsigned short* __restrict__ xb, const unsigned short* __restrict__ WF,
    unsigned short* __restrict__ Qg, unsigned short* __restrict__ Kg,
    unsigned short* __restrict__ Vtg)
{
    __shared__ unsigned short xt[64 * 72];     // x tile, padded (v7-proven banking)
    __shared__ unsigned short wbuf[24 * 512];  // 24 W fragments x 1KB; reused as vt

    const int tid = threadIdx.x;
    const int w = tid >> 6, l = tid & 63, g = l >> 4, n = l & 15;
    const int wm = w & 1, wn = w >> 1;
    const int m0 = blockIdx.x * 64;

    const int xr = tid >> 3, xc = (tid & 7) * 8;   // x stage unit: 16B/thread
    const unsigned short* xrow = &xb[(size_t)(m0 + xr) * D_DIM + xc];

    f32x4 acc[2][3];
    #pragma unroll
    for (int rb = 0; rb < 2; ++rb)
        #pragma unroll
        for (int ct = 0; ct < 3; ++ct) acc[rb][ct] = f32x4{0.f, 0.f, 0.f, 0.f};

    // prologue: stage ks=0 directly, prefetch ks=1, DMA W(0)
    *reinterpret_cast<u16x8*>(&xt[xr * 72 + xc]) =
        *reinterpret_cast<const u16x8*>(xrow);
    u16x8 xnext = *reinterpret_cast<const u16x8*>(xrow + 64);
    #pragma unroll
    for (int j = 0; j < 3; ++j) {
        const int slot = w * 3 + j;
        gload_lds16(WF + ((size_t)slot * 64 + l) * 8, &wbuf[slot * 512]);
    }

#define KITER(ks) {                                                            \
    __syncthreads();  /* B1: x ds_write + W DMA for ks complete */             \
    u16x8 af[2][2], wf[3][2];                                                  \
    _Pragma("unroll")                                                          \
    for (int rb = 0; rb < 2; ++rb)                                             \
        _Pragma("unroll")                                                      \
        for (int kh = 0; kh < 2; ++kh)                                         \
            af[rb][kh] = *reinterpret_cast<const u16x8*>(                      \
                &xt[(wm * 32 + rb * 16 + n) * 72 + kh * 32 + g * 8]);          \
    _Pragma("unroll")                                                          \
    for (int ct = 0; ct < 3; ++ct)                                             \
        _Pragma("unroll")                                                      \
        for (int kh = 0; kh < 2; ++kh)                                         \
            wf[ct][kh] = *reinterpret_cast<const u16x8*>(                      \
                &wbuf[((wn * 3 + ct) * 2 + kh) * 512 + l * 8]);                \
    __syncthreads();  /* B2: reads done -> safe to overwrite */                \
    if ((ks) < 15) {                                                           \
        *reinterpret_cast<u16x8*>(&xt[xr * 72 + xc]) = xnext;                  \
        _Pragma("unroll")                                                      \
        for (int j = 0; j < 3; ++j) {                                          \
            const int slot = w * 3 + j;                                        \
            gload_lds16(WF + (((size_t)((ks) + 1) * 24 + slot) * 64 + l) * 8,  \
                        &wbuf[slot * 512]);                                    \
        }                                                                      \
    }                                                                          \
    if ((ks) + 2 <= 15)                                                        \
        xnext = *reinterpret_cast<const u16x8*>(xrow + ((ks) + 2) * 64);       \
    _Pragma("unroll")                                                          \
    for (int rb = 0; rb < 2; ++rb)                                             \
        _Pragma("unroll")                                                      \
        for (int ct = 0; ct < 3; ++ct) {                                       \
            acc[rb][ct] = mfma_bf16(af[rb][0], wf[ct][0], acc[rb][ct]);        \
            acc[rb][ct] = mfma_bf16(af[rb][1], wf[ct][1], acc[rb][ct]);        \
        }                                                                      \
}

    KITER(0)  KITER(1)  KITER(2)  KITER(3)
    KITER(4)  KITER(5)  KITER(6)  KITER(7)
    KITER(8)  KITER(9)  KITER(10) KITER(11)
    KITER(12) KITER(13) KITER(14) KITER(15)
#undef KITER

    // ---- epilogue: D layout col = lane&15, row = (lane>>4)*4 + reg ----
    // vt reuses wbuf (all wf reads completed at iter-15 B2).
    const int b = m0 >> 11, t0 = m0 & (T_SEQ - 1);
    #pragma unroll
    for (int rb = 0; rb < 2; ++rb)
        #pragma unroll
        for (int ct = 0; ct < 3; ++ct) {
            const int c = wn * 48 + ct * 16 + n;
            #pragma unroll
            for (int r = 0; r < 4; ++r) {
                const int rin = wm * 32 + rb * 16 + g * 4 + r;
                const float val = acc[rb][ct][r];
                if (c < 64)
                    Qg[(size_t)(m0 + rin) * H_DIM + c] = f2bf(val * 0.125f);
                else if (c < 128)
                    Kg[(size_t)(m0 + rin) * H_DIM + (c - 64)] = f2bf(val);
                else
                    wbuf[(c - 128) * 72 + rin] = f2bf(val);   // vt[h][t_local]
            }
        }
    __syncthreads();
    {   // Vt[b][h][t] coalesced: 64h x 64t, one u16x8 per thread
        const int h = tid >> 3, tc = (tid & 7) * 8;
        *reinterpret_cast<u16x8*>(&Vtg[((size_t)(b * 64 + h)) * T_SEQ + t0 + tc]) =
            *reinterpret_cast<const u16x8*>(&wbuf[h * 72 + tc]);
    }
}

// ---------------------------------------------------------------------------
// Kernel 2: causal flash attention (unchanged PASS since round 5).
// ---------------------------------------------------------------------------
__global__ __launch_bounds__(256) void attn_kernel(
    const unsigned short* __restrict__ Qg, const unsigned short* __restrict__ Kg,
    const unsigned short* __restrict__ Vtg, float* __restrict__ out)
{
    __shared__ unsigned short Kl[128 * 72];   // [key][h]
    __shared__ unsigned short Vl[64 * 136];   // [h][key]
    __shared__ float Om[2][64][20];           // merge buffer
    __shared__ float mred[4][64], lred[4][64];

    const int tid = threadIdx.x;
    const int wv = tid >> 6, qg = wv >> 1, kh = wv & 1;
    const int l = tid & 63, g = l >> 4, n = l & 15;

    const int i = blockIdx.x, hi = i >> 8, rest = i & 255;
    const int b = hi * 4 + (rest >> 6), j = rest & 63;
    const int qt = hi ? (63 - j) : j;
    const int q0 = qt * 32;
    const int qrow = q0 + qg * 16 + n;
    const int qmax = q0 + qg * 16 + 15;
    const int nk = (qt >> 2) + 1;

    const unsigned short* Qb = Qg + (size_t)b * T_SEQ * H_DIM;
    const unsigned short* Kb = Kg + (size_t)b * T_SEQ * H_DIM;
    const unsigned short* Vb = Vtg + (size_t)b * H_DIM * T_SEQ;

    const u16x8 qf0 = *reinterpret_cast<const u16x8*>(&Qb[(size_t)qrow * H_DIM + g * 8]);
    const u16x8 qf1 = *reinterpret_cast<const u16x8*>(&Qb[(size_t)qrow * H_DIM + 32 + g * 8]);

    f32x4 oacc[4];
    #pragma unroll
    for (int hb = 0; hb < 4; ++hb) oacc[hb] = f32x4{0.f, 0.f, 0.f, 0.f};
    float mrun = -1e30f, lrun = 0.f;

    u16x8 kst[4], vst[4];
    #pragma unroll
    for (int ii = 0; ii < 4; ++ii) {
        const int u = tid + ii * 256;
        const int kr = u >> 3, kc = (u & 7) * 8;
        const int vh = u >> 4, vc = (u & 15) * 8;
        kst[ii] = *reinterpret_cast<const u16x8*>(&Kb[(size_t)kr * H_DIM + kc]);
        vst[ii] = *reinterpret_cast<const u16x8*>(&Vb[(size_t)vh * T_SEQ + vc]);
    }

    for (int t = 0; t < nk; ++t) {
        __syncthreads();
        #pragma unroll
        for (int ii = 0; ii < 4; ++ii) {
            const int u = tid + ii * 256;
            const int kr = u >> 3, kc = (u & 7) * 8;
            const int vh = u >> 4, vc = (u & 15) * 8;
            *reinterpret_cast<u16x8*>(&Kl[kr * 72 + kc]) = kst[ii];
            *reinterpret_cast<u16x8*>(&Vl[vh * 136 + vc]) = vst[ii];
        }
        __syncthreads();
        if (t + 1 < nk) {
            const int k0n = (t + 1) * 128;
            #pragma unroll
            for (int ii = 0; ii < 4; ++ii) {
                const int u = tid + ii * 256;
                const int kr = u >> 3, kc = (u & 7) * 8;
                const int vh = u >> 4, vc = (u & 15) * 8;
                kst[ii] = *reinterpret_cast<const u16x8*>(&Kb[(size_t)(k0n + kr) * H_DIM + kc]);
                vst[ii] = *reinterpret_cast<const u16x8*>(&Vb[(size_t)vh * T_SEQ + k0n + vc]);
            }
        }

        const int kbase = kh * 64;
        if (t * 128 + kbase <= qmax) {
            f32x4 s[4];
            #pragma unroll
            for (int kb = 0; kb < 4; ++kb) {
                const u16x8 kf0 = *reinterpret_cast<const u16x8*>(&Kl[(kbase + kb * 16 + n) * 72 + g * 8]);
                const u16x8 kf1 = *reinterpret_cast<const u16x8*>(&Kl[(kbase + kb * 16 + n) * 72 + 32 + g * 8]);
                f32x4 z = f32x4{0.f, 0.f, 0.f, 0.f};
                z = mfma_bf16(kf0, qf0, z);
                z = mfma_bf16(kf1, qf1, z);
                s[kb] = z;
            }

            float sv[16];
            float tmax = -1e30f;
            #pragma unroll
            for (int kb = 0; kb < 4; ++kb)
                #pragma unroll
                for (int r = 0; r < 4; ++r) {
                    const int kk = t * 128 + kbase + kb * 16 + g * 4 + r;
                    float v = s[kb][r];
                    v = (kk <= qrow) ? v : -1e30f;
                    sv[kb * 4 + r] = v;
                    tmax = fmaxf(tmax, v);
                }
            tmax = fmaxf(tmax, __shfl_xor(tmax, 16));
            tmax = fmaxf(tmax, __shfl_xor(tmax, 32));
            const float mnew = fmaxf(mrun, tmax);
            const float scale = __expf(mrun - mnew);
            #pragma unroll
            for (int hb = 0; hb < 4; ++hb) oacc[hb] *= scale;
            lrun = lrun * scale;
            mrun = mnew;

            unsigned short pb[16];
            float ps = 0.f;
            #pragma unroll
            for (int q = 0; q < 16; ++q) {
                const float p = (sv[q] > -1e29f) ? __expf(sv[q] - mnew) : 0.f;
                pb[q] = f2bf(p);
                ps += bf2f(pb[q]);
            }
            ps += __shfl_xor(ps, 16);
            ps += __shfl_xor(ps, 32);
            lrun += ps;

            u16x8 pa0, pa1;
            #pragma unroll
            for (int q = 0; q < 8; ++q) { pa0[q] = pb[q]; pa1[q] = pb[8 + q]; }

            #pragma unroll
            for (int hb = 0; hb < 4; ++hb) {
                const unsigned short* vp = &Vl[(hb * 16 + n) * 136 + kbase + 4 * g];
                const u16x4 a0 = *reinterpret_cast<const u16x4*>(vp);
                const u16x4 a1 = *reinterpret_cast<const u16x4*>(vp + 16);
                const u16x4 b0 = *reinterpret_cast<const u16x4*>(vp + 32);
                const u16x4 b1 = *reinterpret_cast<const u16x4*>(vp + 48);
                const u16x8 vf0 = { a0[0], a0[1], a0[2], a0[3], a1[0], a1[1], a1[2], a1[3] };
                const u16x8 vf1 = { b0[0], b0[1], b0[2], b0[3], b1[0], b1[1], b1[2], b1[3] };
                oacc[hb] = mfma_bf16(vf0, pa0, oacc[hb]);
                oacc[hb] = mfma_bf16(vf1, pa1, oacc[hb]);
            }
        }
    }

    // cross-wave (kh pair) merge
    mred[wv][l] = mrun;
    lred[wv][l] = lrun;
    __syncthreads();
    const float m0v = mred[qg * 2][l],     l0v = lred[qg * 2][l];
    const float m1v = mred[qg * 2 + 1][l], l1v = lred[qg * 2 + 1][l];
    const float M = fmaxf(m0v, m1v);
    const float alpha = __expf(mrun - M);
    const float Lsum = l0v * __expf(m0v - M) + l1v * __expf(m1v - M);
    #pragma unroll
    for (int hb = 0; hb < 4; ++hb) oacc[hb] *= alpha;

    if (kh == 1) {
        #pragma unroll
        for (int hb = 0; hb < 4; ++hb)
            *reinterpret_cast<f32x4*>(&Om[qg][l][hb * 4]) = oacc[hb];
    }
    __syncthreads();
    if (kh == 0) {
        const float inv = 1.0f / Lsum;
        #pragma unroll
        for (int hb = 0; hb < 4; ++hb) {
            const f32x4 o2 = *reinterpret_cast<const f32x4*>(&Om[qg][l][hb * 4]);
            float4 o;
            o.x = (oacc[hb][0] + o2[0]) * inv;
            o.y = (oacc[hb][1] + o2[1]) * inv;
            o.z = (oacc[hb][2] + o2[2]) * inv;
            o.w = (oacc[hb][3] + o2[3]) * inv;
            *reinterpret_cast<float4*>(
                &out[((size_t)b * T_SEQ + qrow) * H_DIM + hb * 16 + 4 * g]) = o;
        }
    }
}

// ---------------------------------------------------------------------------
extern "C" void kernel_launch(void* const* d_in, const int* in_sizes, int n_in,
                              void* d_out, int out_size, void* d_ws, size_t ws_size,
                              hipStream_t stream) {
    const float* x  = (const float*)d_in[0];
    const float* Wq = (const float*)d_in[1];
    const float* Wk = (const float*)d_in[2];
    const float* Wv = (const float*)d_in[3];

    unsigned short* Qg  = (unsigned short*)d_ws;
    unsigned short* Kg  = Qg + (size_t)M_TOT * H_DIM;
    unsigned short* Vtg = Kg + (size_t)M_TOT * H_DIM;
    unsigned short* WF  = Vtg + (size_t)M_TOT * H_DIM;       // 384 KB
    unsigned short* xb  = WF + (size_t)16 * 24 * 64 * 8;     // 32 MB bf16 x
    float* o = (float*)d_out;

    prep_kernel<<<1072, 256, 0, stream>>>(x, Wq, Wk, Wv, xb, WF);
    qkv_proj_kernel<<<M_TOT / 64, 512, 0, stream>>>(xb, WF, Qg, Kg, Vtg);
    attn_kernel<<<512, 256, 0, stream>>>(Qg, Kg, Vtg, o);
}

// Round 13
// 57.546 us; speedup vs baseline: 1.0880x; 1.0880x over previous
//
#include <hip/hip_runtime.h>

#define D_DIM 1024
#define H_DIM 64
#define T_SEQ 2048
#define B_SZ  8
#define M_TOT (B_SZ * T_SEQ)

typedef __attribute__((ext_vector_type(4))) float f32x4;
typedef __attribute__((ext_vector_type(8))) short s16x8;
typedef __attribute__((ext_vector_type(8))) unsigned short u16x8;
typedef __attribute__((ext_vector_type(4))) unsigned short u16x4;

__device__ __forceinline__ unsigned short f2bf(float x) {
    union { float f; unsigned u; } v; v.f = x;
    unsigned r = (v.u + 0x7FFFu + ((v.u >> 16) & 1u)) >> 16;   // RNE
    return (unsigned short)r;
}
__device__ __forceinline__ float bf2f(unsigned short u) {
    union { unsigned u; float f; } v; v.u = ((unsigned)u) << 16; return v.f;
}
__device__ __forceinline__ f32x4 mfma_bf16(u16x8 a, u16x8 b, f32x4 c) {
    return __builtin_amdgcn_mfma_f32_16x16x32_bf16(
        __builtin_bit_cast(s16x8, a), __builtin_bit_cast(s16x8, b), c, 0, 0, 0);
}

// ---------------------------------------------------------------------------
// Kernel 0: W fp32 [1024][64] (x3) -> WF bf16 in MFMA B-fragment order.
// fid = ks*24 + (mat*4+colTile)*2 + kh ; each fragment = contiguous 1KB.
// ---------------------------------------------------------------------------
__global__ __launch_bounds__(256) void wtrans_kernel(
    const float* __restrict__ Wq, const float* __restrict__ Wk,
    const float* __restrict__ Wv, unsigned short* __restrict__ WF)
{
    __shared__ unsigned short tw[64 * 72];
    const int mat = blockIdx.x / 16;
    const int k0  = (blockIdx.x % 16) * 64;
    const int ks  = k0 >> 6;
    const float* W = (mat == 0) ? Wq : (mat == 1) ? Wk : Wv;
    const int tid = threadIdx.x;

    {
        const int r = tid >> 2, c0 = (tid & 3) * 16;
        #pragma unroll
        for (int jj = 0; jj < 4; ++jj) {
            float4 v = *reinterpret_cast<const float4*>(&W[(size_t)(k0 + r) * H_DIM + c0 + jj * 4]);
            u16x4 u = { f2bf(v.x), f2bf(v.y), f2bf(v.z), f2bf(v.w) };
            *reinterpret_cast<u16x4*>(&tw[r * 72 + c0 + jj * 4]) = u;
        }
    }
    __syncthreads();
    #pragma unroll
    for (int sb = 0; sb < 2; ++sb) {
        const int s    = sb * 256 + tid;
        const int ct_l = s >> 7;
        const int kh   = (s >> 6) & 1;
        const int lane = s & 63;
        const int gg = lane >> 4, nn = lane & 15;
        const int cl = ct_l * 16 + nn;
        const int kl = kh * 32 + gg * 8;
        unsigned short tmp[8];
        #pragma unroll
        for (int t = 0; t < 8; ++t) tmp[t] = tw[(kl + t) * 72 + cl];
        const int fid = ks * 24 + (mat * 4 + ct_l) * 2 + kh;
        *reinterpret_cast<u16x8*>(&WF[((size_t)fid * 64 + lane) * 8]) =
            *reinterpret_cast<const u16x8*>(tmp);
    }
}

// ---------------------------------------------------------------------------
// Kernel 1: QKV projection v9.  M=16/block, grid 1024 (4 blocks/CU staggered).
// ONE deep x burst (16 float4/thread in flight) -> one barrier ->
// BARRIER-FREE fully-unrolled K-loop (W frags from L2, 1-deep reg prefetch).
// No vmcnt(0) drains inside the loop => loads stay in flight; the 4 staggered
// blocks/CU keep HBM busy while others compute (duty-cycle fix).
// ---------------------------------------------------------------------------
__global__ __launch_bounds__(256, 4) void qkv_proj_kernel(
    const float* __restrict__ x, const unsigned short* __restrict__ WF,
    unsigned short* __restrict__ Qg, unsigned short* __restrict__ Kg,
    unsigned short* __restrict__ Vtg)
{
    __shared__ unsigned short xs[16 * 1040];   // [16][1024+16] bf16 = 33280 B
    __shared__ unsigned short vt[64 * 24];     // epilogue V transpose

    const int tid = threadIdx.x;
    const int w = tid >> 6, l = tid & 63, g = l >> 4, n = l & 15;
    const int m0 = blockIdx.x * 16;

    // ---- stage whole 16x1024 x panel: 16 float4/thread, single burst ----
    {
        const float4* x4 = reinterpret_cast<const float4*>(x + (size_t)m0 * D_DIM);
        float4 st[16];
        #pragma unroll
        for (int j = 0; j < 16; ++j) st[j] = x4[j * 256 + tid];
        #pragma unroll
        for (int j = 0; j < 16; ++j) {
            const int u = j * 256 + tid;            // float4 unit 0..4095
            const int row = u >> 8, col = (u & 255) * 4;
            u16x4 v = { f2bf(st[j].x), f2bf(st[j].y), f2bf(st[j].z), f2bf(st[j].w) };
            *reinterpret_cast<u16x4*>(&xs[row * 1040 + col]) = v;
        }
    }
    __syncthreads();   // the ONLY pre-epilogue barrier

    // ---- barrier-free K-loop; W frags direct from WF (L2-resident) ----
    const unsigned short* wfb = WF + ((size_t)(w * 3) * 2 * 64 + l) * 8;
#define WFRAG(ks, ct, kh) \
    (*reinterpret_cast<const u16x8*>(wfb + (((ks) * 24 + (ct) * 2 + (kh)) * 64) * 8))

    u16x8 cw00 = WFRAG(0, 0, 0), cw10 = WFRAG(0, 1, 0), cw20 = WFRAG(0, 2, 0);
    u16x8 cw01 = WFRAG(0, 0, 1), cw11 = WFRAG(0, 1, 1), cw21 = WFRAG(0, 2, 1);

    f32x4 acc0 = {0.f,0.f,0.f,0.f}, acc1 = {0.f,0.f,0.f,0.f}, acc2 = {0.f,0.f,0.f,0.f};

    #pragma unroll
    for (int ks = 0; ks < 16; ++ks) {
        const u16x8 u00 = cw00, u10 = cw10, u20 = cw20;
        const u16x8 u01 = cw01, u11 = cw11, u21 = cw21;
        if (ks < 15) {
            cw00 = WFRAG(ks + 1, 0, 0); cw10 = WFRAG(ks + 1, 1, 0);
            cw20 = WFRAG(ks + 1, 2, 0); cw01 = WFRAG(ks + 1, 0, 1);
            cw11 = WFRAG(ks + 1, 1, 1); cw21 = WFRAG(ks + 1, 2, 1);
        }
        const u16x8 af0 = *reinterpret_cast<const u16x8*>(&xs[n * 1040 + ks * 64 + g * 8]);
        const u16x8 af1 = *reinterpret_cast<const u16x8*>(&xs[n * 1040 + ks * 64 + 32 + g * 8]);
        acc0 = mfma_bf16(af0, u00, acc0);
        acc1 = mfma_bf16(af0, u10, acc1);
        acc2 = mfma_bf16(af0, u20, acc2);
        acc0 = mfma_bf16(af1, u01, acc0);
        acc1 = mfma_bf16(af1, u11, acc1);
        acc2 = mfma_bf16(af1, u21, acc2);
    }
#undef WFRAG

    // ---- epilogue: D layout col = lane&15, row = (lane>>4)*4 + reg ----
    const int b = m0 >> 11, t0 = m0 & (T_SEQ - 1);
    const f32x4 accs[3] = { acc0, acc1, acc2 };
    #pragma unroll
    for (int ct = 0; ct < 3; ++ct) {
        const int c = w * 48 + ct * 16 + n;
        #pragma unroll
        for (int r = 0; r < 4; ++r) {
            const int rin = g * 4 + r;
            const float val = accs[ct][r];
            if (c < 64)
                Qg[(size_t)(m0 + rin) * H_DIM + c] = f2bf(val * 0.125f);
            else if (c < 128)
                Kg[(size_t)(m0 + rin) * H_DIM + (c - 64)] = f2bf(val);
            else
                vt[(c - 128) * 24 + rin] = f2bf(val);
        }
    }
    __syncthreads();
    {   // Vt[b][h][t]: 64h x 16t, one u16x4 per thread
        const int h = tid >> 2, c4 = (tid & 3) * 4;
        *reinterpret_cast<u16x4*>(&Vtg[((size_t)(b * 64 + h)) * T_SEQ + t0 + c4]) =
            *reinterpret_cast<const u16x4*>(&vt[h * 24 + c4]);
    }
}

// ---------------------------------------------------------------------------
// Kernel 2: causal flash attention (unchanged PASS since round 5).
// ---------------------------------------------------------------------------
__global__ __launch_bounds__(256) void attn_kernel(
    const unsigned short* __restrict__ Qg, const unsigned short* __restrict__ Kg,
    const unsigned short* __restrict__ Vtg, float* __restrict__ out)
{
    __shared__ unsigned short Kl[128 * 72];   // [key][h]
    __shared__ unsigned short Vl[64 * 136];   // [h][key]
    __shared__ float Om[2][64][20];           // merge buffer
    __shared__ float mred[4][64], lred[4][64];

    const int tid = threadIdx.x;
    const int wv = tid >> 6, qg = wv >> 1, kh = wv & 1;
    const int l = tid & 63, g = l >> 4, n = l & 15;

    const int i = blockIdx.x, hi = i >> 8, rest = i & 255;
    const int b = hi * 4 + (rest >> 6), j = rest & 63;
    const int qt = hi ? (63 - j) : j;
    const int q0 = qt * 32;
    const int qrow = q0 + qg * 16 + n;
    const int qmax = q0 + qg * 16 + 15;
    const int nk = (qt >> 2) + 1;

    const unsigned short* Qb = Qg + (size_t)b * T_SEQ * H_DIM;
    const unsigned short* Kb = Kg + (size_t)b * T_SEQ * H_DIM;
    const unsigned short* Vb = Vtg + (size_t)b * H_DIM * T_SEQ;

    const u16x8 qf0 = *reinterpret_cast<const u16x8*>(&Qb[(size_t)qrow * H_DIM + g * 8]);
    const u16x8 qf1 = *reinterpret_cast<const u16x8*>(&Qb[(size_t)qrow * H_DIM + 32 + g * 8]);

    f32x4 oacc[4];
    #pragma unroll
    for (int hb = 0; hb < 4; ++hb) oacc[hb] = f32x4{0.f, 0.f, 0.f, 0.f};
    float mrun = -1e30f, lrun = 0.f;

    u16x8 kst[4], vst[4];
    #pragma unroll
    for (int ii = 0; ii < 4; ++ii) {
        const int u = tid + ii * 256;
        const int kr = u >> 3, kc = (u & 7) * 8;
        const int vh = u >> 4, vc = (u & 15) * 8;
        kst[ii] = *reinterpret_cast<const u16x8*>(&Kb[(size_t)kr * H_DIM + kc]);
        vst[ii] = *reinterpret_cast<const u16x8*>(&Vb[(size_t)vh * T_SEQ + vc]);
    }

    for (int t = 0; t < nk; ++t) {
        __syncthreads();
        #pragma unroll
        for (int ii = 0; ii < 4; ++ii) {
            const int u = tid + ii * 256;
            const int kr = u >> 3, kc = (u & 7) * 8;
            const int vh = u >> 4, vc = (u & 15) * 8;
            *reinterpret_cast<u16x8*>(&Kl[kr * 72 + kc]) = kst[ii];
            *reinterpret_cast<u16x8*>(&Vl[vh * 136 + vc]) = vst[ii];
        }
        __syncthreads();
        if (t + 1 < nk) {
            const int k0n = (t + 1) * 128;
            #pragma unroll
            for (int ii = 0; ii < 4; ++ii) {
                const int u = tid + ii * 256;
                const int kr = u >> 3, kc = (u & 7) * 8;
                const int vh = u >> 4, vc = (u & 15) * 8;
                kst[ii] = *reinterpret_cast<const u16x8*>(&Kb[(size_t)(k0n + kr) * H_DIM + kc]);
                vst[ii] = *reinterpret_cast<const u16x8*>(&Vb[(size_t)vh * T_SEQ + k0n + vc]);
            }
        }

        const int kbase = kh * 64;
        if (t * 128 + kbase <= qmax) {
            f32x4 s[4];
            #pragma unroll
            for (int kb = 0; kb < 4; ++kb) {
                const u16x8 kf0 = *reinterpret_cast<const u16x8*>(&Kl[(kbase + kb * 16 + n) * 72 + g * 8]);
                const u16x8 kf1 = *reinterpret_cast<const u16x8*>(&Kl[(kbase + kb * 16 + n) * 72 + 32 + g * 8]);
                f32x4 z = f32x4{0.f, 0.f, 0.f, 0.f};
                z = mfma_bf16(kf0, qf0, z);
                z = mfma_bf16(kf1, qf1, z);
                s[kb] = z;
            }

            float sv[16];
            float tmax = -1e30f;
            #pragma unroll
            for (int kb = 0; kb < 4; ++kb)
                #pragma unroll
                for (int r = 0; r < 4; ++r) {
                    const int kk = t * 128 + kbase + kb * 16 + g * 4 + r;
                    float v = s[kb][r];
                    v = (kk <= qrow) ? v : -1e30f;
                    sv[kb * 4 + r] = v;
                    tmax = fmaxf(tmax, v);
                }
            tmax = fmaxf(tmax, __shfl_xor(tmax, 16));
            tmax = fmaxf(tmax, __shfl_xor(tmax, 32));
            const float mnew = fmaxf(mrun, tmax);
            const float scale = __expf(mrun - mnew);
            #pragma unroll
            for (int hb = 0; hb < 4; ++hb) oacc[hb] *= scale;
            lrun = lrun * scale;
            mrun = mnew;

            unsigned short pb[16];
            float ps = 0.f;
            #pragma unroll
            for (int q = 0; q < 16; ++q) {
                const float p = (sv[q] > -1e29f) ? __expf(sv[q] - mnew) : 0.f;
                pb[q] = f2bf(p);
                ps += bf2f(pb[q]);
            }
            ps += __shfl_xor(ps, 16);
            ps += __shfl_xor(ps, 32);
            lrun += ps;

            u16x8 pa0, pa1;
            #pragma unroll
            for (int q = 0; q < 8; ++q) { pa0[q] = pb[q]; pa1[q] = pb[8 + q]; }

            #pragma unroll
            for (int hb = 0; hb < 4; ++hb) {
                const unsigned short* vp = &Vl[(hb * 16 + n) * 136 + kbase + 4 * g];
                const u16x4 a0 = *reinterpret_cast<const u16x4*>(vp);
                const u16x4 a1 = *reinterpret_cast<const u16x4*>(vp + 16);
                const u16x4 b0 = *reinterpret_cast<const u16x4*>(vp + 32);
                const u16x4 b1 = *reinterpret_cast<const u16x4*>(vp + 48);
                const u16x8 vf0 = { a0[0], a0[1], a0[2], a0[3], a1[0], a1[1], a1[2], a1[3] };
                const u16x8 vf1 = { b0[0], b0[1], b0[2], b0[3], b1[0], b1[1], b1[2], b1[3] };
                oacc[hb] = mfma_bf16(vf0, pa0, oacc[hb]);
                oacc[hb] = mfma_bf16(vf1, pa1, oacc[hb]);
            }
        }
    }

    // cross-wave (kh pair) merge
    mred[wv][l] = mrun;
    lred[wv][l] = lrun;
    __syncthreads();
    const float m0v = mred[qg * 2][l],     l0v = lred[qg * 2][l];
    const float m1v = mred[qg * 2 + 1][l], l1v = lred[qg * 2 + 1][l];
    const float M = fmaxf(m0v, m1v);
    const float alpha = __expf(mrun - M);
    const float Lsum = l0v * __expf(m0v - M) + l1v * __expf(m1v - M);
    #pragma unroll
    for (int hb = 0; hb < 4; ++hb) oacc[hb] *= alpha;

    if (kh == 1) {
        #pragma unroll
        for (int hb = 0; hb < 4; ++hb)
            *reinterpret_cast<f32x4*>(&Om[qg][l][hb * 4]) = oacc[hb];
    }
    __syncthreads();
    if (kh == 0) {
        const float inv = 1.0f / Lsum;
        #pragma unroll
        for (int hb = 0; hb < 4; ++hb) {
            const f32x4 o2 = *reinterpret_cast<const f32x4*>(&Om[qg][l][hb * 4]);
            float4 o;
            o.x = (oacc[hb][0] + o2[0]) * inv;
            o.y = (oacc[hb][1] + o2[1]) * inv;
            o.z = (oacc[hb][2] + o2[2]) * inv;
            o.w = (oacc[hb][3] + o2[3]) * inv;
            *reinterpret_cast<float4*>(
                &out[((size_t)b * T_SEQ + qrow) * H_DIM + hb * 16 + 4 * g]) = o;
        }
    }
}

// ---------------------------------------------------------------------------
extern "C" void kernel_launch(void* const* d_in, const int* in_sizes, int n_in,
                              void* d_out, int out_size, void* d_ws, size_t ws_size,
                              hipStream_t stream) {
    const float* x  = (const float*)d_in[0];
    const float* Wq = (const float*)d_in[1];
    const float* Wk = (const float*)d_in[2];
    const float* Wv = (const float*)d_in[3];

    unsigned short* Qg  = (unsigned short*)d_ws;
    unsigned short* Kg  = Qg + (size_t)M_TOT * H_DIM;
    unsigned short* Vtg = Kg + (size_t)M_TOT * H_DIM;
    unsigned short* WF  = Vtg + (size_t)M_TOT * H_DIM;   // 384 KB
    float* o = (float*)d_out;

    wtrans_kernel<<<48, 256, 0, stream>>>(Wq, Wk, Wv, WF);
    qkv_proj_kernel<<<M_TOT / 16, 256, 0, stream>>>(x, WF, Qg, Kg, Vtg);
    attn_kernel<<<512, 256, 0, stream>>>(Qg, Kg, Vtg, o);
}